// Round 8
// baseline (339.075 us; speedup 1.0000x reference)
//
#include <hip/hip_runtime.h>

#define SEQ 512
#define BATCH 8192
#define LOG2E  1.44269504088896340736f
#define LOG2E2 2.88539008177792681472f   // 2*log2(e)

typedef _Float16 f16x8 __attribute__((ext_vector_type(8)));
typedef float    f32x4 __attribute__((ext_vector_type(4)));

__device__ __forceinline__ float fexp2(float x) { return __builtin_amdgcn_exp2f(x); }
__device__ __forceinline__ float frcp(float x)  { return __builtin_amdgcn_rcpf(x); }

// MFMA LSTM, split-precision. One wave per 16 batch elements. Pipelined step t
// computes L0[t+1] and L1[t]; both read the same v = [x[t+1]; h1[t]; h2[t-1]]
// (22 rows). z(80) = W(80x22)·v via 16x16x32_f16 MFMA, 5 row-tiles.
// Precision: W = W_hi + W_lo (f16 pair), v = v_hi + v_lo (f16 pair);
// z = W_hi·v_hi + W_lo·v_hi + W_hi·v_lo + bias(C)  -> ~22-bit effective.
// W row order: rows 4P..4P+3 = (i,f,g,o) of pair P; P<10 -> (L0, unit P),
// P>=10 -> (L1, unit P-10). D layout: col=lane&15=elem, row=q*4+r ->
// lane (q,e) owns pairs {4T+q}, all 4 gates in its 4 acc regs (lane-local
// c/h update). K-map immunity: A-pack and B-read use the same (q,j)->k map.
// LDS v-buffer: [buf][elem][80] f16 — rows 0..21 hi (22..39 zero),
// rows 40..61 lo (62..79 zero); ping-pong, no barriers in the loop.
__global__ __launch_bounds__(64) void lstm2_fc_mfma(
    const float* __restrict__ x,
    const float* __restrict__ w_ih0, const float* __restrict__ w_hh0,
    const float* __restrict__ b_ih0, const float* __restrict__ b_hh0,
    const float* __restrict__ w_ih1, const float* __restrict__ w_hh1,
    const float* __restrict__ b_ih1, const float* __restrict__ b_hh1,
    const float* __restrict__ fc_w, const float* __restrict__ fc_b,
    float* __restrict__ out)
{
    __shared__ __align__(16) _Float16 vlds[2][16][80];
    __shared__ float hfc[16][10];

    const int lane = threadIdx.x;
    const int e    = lane & 15;      // elem column / A-row-in-tile
    const int q    = lane >> 4;      // K-chunk for A/B; row-quad for C/D
    const int Eb   = blockIdx.x * 16;

    // ---- zero-init both v buffers (pad K-rows must be 0) ----
    {
        unsigned* p = (unsigned*)&vlds[0][0][0];      // 5120 B = 1280 dwords
        for (int i = lane; i < 1280; i += 64) p[i] = 0u;
    }

    // ---- A fragments hi/lo (prescaled) + C bias + pair flags ----
    f16x8 ahi[5], alo[5];
    f32x4 cb[5];
    bool  l1p[5];
    #pragma unroll
    for (int T = 0; T < 5; ++T) {
        const int Ra = T * 16 + e;                    // A: row in tile = e
        const int Pa = Ra >> 2, Ga = Ra & 3;
        const int La = (Pa >= 10);
        const int Ua = Pa - La * 10;
        const int wr = Ga * 10 + Ua;                  // torch row in 40-row block
        const float m = (Ga == 2) ? LOG2E2 : -LOG2E;
        #pragma unroll
        for (int j = 0; j < 8; ++j) {
            const int k = q * 8 + j;                  // same map as B-read below
            float w = 0.0f;
            if (k < 2)        w = La ? 0.0f : w_ih0[wr * 2 + k];
            else if (k < 12)  w = La ? w_ih1[wr * 10 + (k - 2)] : w_hh0[wr * 10 + (k - 2)];
            else if (k < 22)  w = La ? w_hh1[wr * 10 + (k - 12)] : 0.0f;
            const float wm = m * w;
            const _Float16 wh = (_Float16)wm;
            ahi[T][j] = wh;
            alo[T][j] = (_Float16)(wm - (float)wh);
        }
        const int Pc = T * 4 + q;                     // C/D: pair = 4T+q
        l1p[T] = (Pc >= 10);
        const int Lc = (Pc >= 10);
        const int Uc = Pc - Lc * 10;
        #pragma unroll
        for (int r = 0; r < 4; ++r) {
            const int wrc = r * 10 + Uc;
            const float mc = (r == 2) ? LOG2E2 : -LOG2E;
            cb[T][r] = mc * (Lc ? (b_ih1[wrc] + b_hh1[wrc])
                                : (b_ih0[wrc] + b_hh0[wrc]));
        }
    }

    __syncthreads();
    // write x[0] (hi+lo) into buf0
    {
        const float2 x0 = *(const float2*)(x + ((size_t)Eb + e) * 2);
        if (q == 0) {
            const _Float16 xa = (_Float16)x0.x, xb = (_Float16)x0.y;
            vlds[0][e][0]  = xa;  vlds[0][e][1]  = xb;
            vlds[0][e][40] = (_Float16)(x0.x - (float)xa);
            vlds[0][e][41] = (_Float16)(x0.y - (float)xb);
        }
    }
    __syncthreads();

    float cst[5] = {0.f, 0.f, 0.f, 0.f, 0.f};
    float hT[5];

    // per-tile activation: 4 gates from acc ZZ, 4-way shared rcp, c update
#define ACT(T, ZZ, SUP)                                                        \
    {                                                                          \
        const float d0 = 1.0f + fexp2(ZZ[0]);                                  \
        const float d1 = 1.0f + fexp2(ZZ[1]);                                  \
        const float d2 = 1.0f + fexp2(ZZ[2]);                                  \
        const float d3 = 1.0f + fexp2(ZZ[3]);                                  \
        const float m1 = d0 * d1, m2 = d2 * d3;                                \
        const float pq_ = frcp(m1 * m2);                                       \
        const float pif = m2 * pq_, pgo = m1 * pq_;                            \
        const float si = d1 * pif, sf = d0 * pif;                              \
        const float tg = fmaf(-2.0f, d3 * pgo, 1.0f);                          \
        sO[T] = d2 * pgo;                                                      \
        float cn = fmaf(sf, cst[T], si * tg);                                  \
        if (SUP) cn = l1p[T] ? 0.0f : cn;  /* prologue: L1 pairs stay 0 */     \
        cst[T] = cn;                                                           \
        eC[T] = 1.0f + fexp2(LOG2E2 * cn);                                     \
    }

    // one pipelined step: consume vlds[CUR]=v_t, produce vlds[NXT]=v_{t+1}
#define STEP(CUR, NXT, T2, SUP)                                                \
    {                                                                          \
        const float2 xn = *(const float2*)(x + ((size_t)(T2) * BATCH + Eb + e) * 2); \
        const f16x8 bh = *(const f16x8*)&vlds[CUR][e][q * 8];                  \
        const f16x8 bl = *(const f16x8*)&vlds[CUR][e][40 + q * 8];             \
        f32x4 z0 = __builtin_amdgcn_mfma_f32_16x16x32_f16(ahi[0], bh, cb[0], 0, 0, 0); \
        f32x4 z1 = __builtin_amdgcn_mfma_f32_16x16x32_f16(ahi[1], bh, cb[1], 0, 0, 0); \
        f32x4 z2 = __builtin_amdgcn_mfma_f32_16x16x32_f16(ahi[2], bh, cb[2], 0, 0, 0); \
        f32x4 z3 = __builtin_amdgcn_mfma_f32_16x16x32_f16(ahi[3], bh, cb[3], 0, 0, 0); \
        f32x4 z4 = __builtin_amdgcn_mfma_f32_16x16x32_f16(ahi[4], bh, cb[4], 0, 0, 0); \
        z0 = __builtin_amdgcn_mfma_f32_16x16x32_f16(alo[0], bh, z0, 0, 0, 0);  \
        z1 = __builtin_amdgcn_mfma_f32_16x16x32_f16(alo[1], bh, z1, 0, 0, 0);  \
        z2 = __builtin_amdgcn_mfma_f32_16x16x32_f16(alo[2], bh, z2, 0, 0, 0);  \
        z3 = __builtin_amdgcn_mfma_f32_16x16x32_f16(alo[3], bh, z3, 0, 0, 0);  \
        z4 = __builtin_amdgcn_mfma_f32_16x16x32_f16(alo[4], bh, z4, 0, 0, 0);  \
        z0 = __builtin_amdgcn_mfma_f32_16x16x32_f16(ahi[0], bl, z0, 0, 0, 0);  \
        z1 = __builtin_amdgcn_mfma_f32_16x16x32_f16(ahi[1], bl, z1, 0, 0, 0);  \
        z2 = __builtin_amdgcn_mfma_f32_16x16x32_f16(ahi[2], bl, z2, 0, 0, 0);  \
        z3 = __builtin_amdgcn_mfma_f32_16x16x32_f16(ahi[3], bl, z3, 0, 0, 0);  \
        z4 = __builtin_amdgcn_mfma_f32_16x16x32_f16(ahi[4], bl, z4, 0, 0, 0);  \
        float eC[5], sO[5];                                                    \
        ACT(0, z0, SUP) ACT(1, z1, SUP) ACT(2, z2, SUP)                        \
        ACT(3, z3, SUP) ACT(4, z4, SUP)                                        \
        const float p01 = frcp(eC[0] * eC[1]);                                 \
        const float p23 = frcp(eC[2] * eC[3]);                                 \
        const float p4  = frcp(eC[4]);                                         \
        hT[0] = sO[0] * fmaf(-2.0f, eC[1] * p01, 1.0f);                        \
        hT[1] = sO[1] * fmaf(-2.0f, eC[0] * p01, 1.0f);                        \
        hT[2] = sO[2] * fmaf(-2.0f, eC[3] * p23, 1.0f);                        \
        hT[3] = sO[3] * fmaf(-2.0f, eC[2] * p23, 1.0f);                        \
        hT[4] = sO[4] * fmaf(-2.0f, p4, 1.0f);                                 \
        _Pragma("unroll")                                                      \
        for (int T = 0; T < 5; ++T) {                                          \
            const _Float16 hh = (_Float16)hT[T];                               \
            vlds[NXT][e][2  + 4 * T + q] = hh;                                 \
            vlds[NXT][e][42 + 4 * T + q] = (_Float16)(hT[T] - (float)hh);      \
        }                                                                      \
        if (q == 0) {                                                          \
            const _Float16 xh = (_Float16)xn.x, xg = (_Float16)xn.y;           \
            vlds[NXT][e][0]  = xh;  vlds[NXT][e][1]  = xg;                     \
            vlds[NXT][e][40] = (_Float16)(xn.x - (float)xh);                   \
            vlds[NXT][e][41] = (_Float16)(xn.y - (float)xg);                   \
        }                                                                      \
    }

    // prologue (t = -1): v = [x0, 0, 0] -> h1[0] into buf1; L1 state stays 0
    STEP(0, 1, 1, 1)

    // main: 512 steps, ping-pong buffers
    for (int t = 0; t < SEQ; t += 2) {
        const int ta = (t + 2 < SEQ) ? t + 2 : SEQ - 1;
        const int tb = (t + 3 < SEQ) ? t + 3 : SEQ - 1;
        STEP(1, 0, ta, 0)
        STEP(0, 1, tb, 0)
    }
#undef STEP
#undef ACT

    // ---- FC: L1 pairs of the last step hold h2[511] ----
    // tile2: pair 8+q -> L1 iff q>=2, unit q-2   (round-7 bug: wrote [q])
    if (q >= 2) hfc[e][q - 2] = hT[2];
    hfc[e][2 + q] = hT[3];                        // pair 12+q -> unit 2+q
    hfc[e][6 + q] = hT[4];                        // pair 16+q -> unit 6+q
    __syncthreads();
    if (lane < 32) {
        const int ee = lane >> 1, jj = lane & 1;
        float acc = fc_b[jj];
        #pragma unroll
        for (int u = 0; u < 10; ++u)
            acc = fmaf(fc_w[jj * 10 + u], hfc[ee][u], acc);
        out[((size_t)Eb + ee) * 2 + jj] = acc;
    }
}

extern "C" void kernel_launch(void* const* d_in, const int* in_sizes, int n_in,
                              void* d_out, int out_size, void* d_ws, size_t ws_size,
                              hipStream_t stream) {
    const float* x     = (const float*)d_in[0];
    const float* w_ih0 = (const float*)d_in[1];
    const float* w_hh0 = (const float*)d_in[2];
    const float* b_ih0 = (const float*)d_in[3];
    const float* b_hh0 = (const float*)d_in[4];
    const float* w_ih1 = (const float*)d_in[5];
    const float* w_hh1 = (const float*)d_in[6];
    const float* b_ih1 = (const float*)d_in[7];
    const float* b_hh1 = (const float*)d_in[8];
    const float* fc_w  = (const float*)d_in[9];
    const float* fc_b  = (const float*)d_in[10];
    float* out = (float*)d_out;

    const int threads = 64;                   // 1 wave = 16 batch elements
    const int blocks  = BATCH / 16;           // 512 blocks -> 2 waves/CU
    lstm2_fc_mfma<<<blocks, threads, 0, stream>>>(
        x, w_ih0, w_hh0, b_ih0, b_hh0,
        w_ih1, w_hh1, b_ih1, b_hh1, fc_w, fc_b, out);
}

// Round 9
// 226.648 us; speedup vs baseline: 1.4960x; 1.4960x over previous
//
#include <hip/hip_runtime.h>

#define SEQ 512
#define BATCH 8192
#define LOG2E  1.44269504088896340736f
#define LOG2E2 2.88539008177792681472f   // 2*log2(e)

typedef _Float16 f16x8 __attribute__((ext_vector_type(8)));
typedef float    f32x4 __attribute__((ext_vector_type(4)));

__device__ __forceinline__ float fexp2(float x) { return __builtin_amdgcn_exp2f(x); }
__device__ __forceinline__ float frcp(float x)  { return __builtin_amdgcn_rcpf(x); }

// MFMA LSTM, all-register recurrence. One wave per 16 batch elements.
// Pipelined step t computes L0[t+1] and L1[t]; both read the same
// v = [x[t+1]; h1[t]; h2[t-1]] -> z(80) = W(80x22-perm)·v via 5x
// mfma_f32_16x16x32_f16, split precision (W=Whi+Wlo, v=vhi+vlo,
// z = Whi·vhi + Wlo·vhi + Whi·vlo + bias) — verified r8, absmax 6e-5.
//
// KEY LAYOUT: pair P=4T+q (P<10 -> (L0,unit P), else (L1,unit P-10)) is
// assigned v-row k = 8q + (2+T). D gives lane (q,e) exactly pairs {4T+q}
// (all 4 gates in its 4 acc regs), and B needs lane (q,e) to hold
// v[8q+j] in slot j — so producer lane == consumer lane for every h:
// the recurrence is bh[2+T] = (f16)hT[T], PURE REGISTERS. No LDS, no
// bpermute, no lgkm waits, no bank conflicts in the loop (r8 had 1.7e7).
// x occupies k=0,1 (q=0 lanes only); slots j=7 (and j=0,1 for q>=1) stay 0.
// A columns are packed with the SAME (q,j)->k map (k-map immunity, r8).
// x is prefetched in 8-step register chunks, ping-pong, static indexing.
__global__ __launch_bounds__(64) void lstm2_fc_mfma(
    const float* __restrict__ x,
    const float* __restrict__ w_ih0, const float* __restrict__ w_hh0,
    const float* __restrict__ b_ih0, const float* __restrict__ b_hh0,
    const float* __restrict__ w_ih1, const float* __restrict__ w_hh1,
    const float* __restrict__ b_ih1, const float* __restrict__ b_hh1,
    const float* __restrict__ fc_w, const float* __restrict__ fc_b,
    float* __restrict__ out)
{
    __shared__ float hfc[16][10];

    const int lane = threadIdx.x;
    const int e    = lane & 15;      // elem column / A-row-in-tile
    const int q    = lane >> 4;      // K-chunk for A/B; row-quad for C/D
    const int Eb   = blockIdx.x * 16;
    const bool qz  = (q == 0);

    // ---- A fragments hi/lo (prescaled) + C bias ----
    f16x8 ahi[5], alo[5];
    f32x4 cb[5];
    bool  l1p[5];
    #pragma unroll
    for (int T = 0; T < 5; ++T) {
        const int Pa = 4 * T + (e >> 2), Ga = e & 3;   // A row e -> pair/gate
        const int La = (Pa >= 10);
        const int Ua = Pa - La * 10;
        const int wr = Ga * 10 + Ua;                   // torch row in 40-block
        const float m = (Ga == 2) ? LOG2E2 : -LOG2E;
        #pragma unroll
        for (int j = 0; j < 8; ++j) {
            const int k = q * 8 + j;
            float w = 0.0f;
            if (k < 2) {                               // x slots (q==0, j<2)
                w = La ? 0.0f : w_ih0[wr * 2 + k];
            } else if (j >= 2 && j <= 6) {             // pair p = 4*(j-2)+q
                const int p = 4 * (j - 2) + q;
                if (p < 10) w = La ? w_ih1[wr * 10 + p] : w_hh0[wr * 10 + p];
                else        w = La ? w_hh1[wr * 10 + (p - 10)] : 0.0f;
            }
            const float wm = m * w;
            const _Float16 wh = (_Float16)wm;
            ahi[T][j] = wh;
            alo[T][j] = (_Float16)(wm - (float)wh);
        }
        const int Pc = 4 * T + q;                      // C/D pair for this lane
        l1p[T] = (Pc >= 10);
        const int Lc = (Pc >= 10);
        const int Uc = Pc - Lc * 10;
        #pragma unroll
        for (int r = 0; r < 4; ++r) {
            const int wrc = r * 10 + Uc;
            const float mc = (r == 2) ? LOG2E2 : -LOG2E;
            cb[T][r] = mc * (Lc ? (b_ih1[wrc] + b_hh1[wrc])
                                : (b_ih0[wrc] + b_hh0[wrc]));
        }
    }

    // ---- B state registers ----
    f16x8 bh, bl;
    #pragma unroll
    for (int j = 0; j < 8; ++j) { bh[j] = (_Float16)0.f; bl[j] = (_Float16)0.f; }

    // ---- x prefetch: x[0], x[1], then 8-step chunks ----
    const float* xe = x + ((size_t)Eb + e) * 2;
    const float2 x0 = *(const float2*)xe;
    const float2 x1 = *(const float2*)(xe + (size_t)1 * BATCH * 2);
    float2 xr0[8], xr1[8];
    #pragma unroll
    for (int i = 0; i < 8; ++i) xr0[i] = *(const float2*)(xe + (size_t)(2 + i) * BATCH * 2);
    #pragma unroll
    for (int i = 0; i < 8; ++i) xr1[i] = *(const float2*)(xe + (size_t)(10 + i) * BATCH * 2);

    // insert x[0] into B (q==0 lanes; others keep 0)
    {
        const _Float16 xa = (_Float16)x0.x, xb2 = (_Float16)x0.y;
        bh[0] = qz ? xa : (_Float16)0.f;
        bh[1] = qz ? xb2 : (_Float16)0.f;
        bl[0] = qz ? (_Float16)(x0.x - (float)xa) : (_Float16)0.f;
        bl[1] = qz ? (_Float16)(x0.y - (float)xb2) : (_Float16)0.f;
    }

    float cst[5] = {0.f, 0.f, 0.f, 0.f, 0.f};
    float hT[5];

#define ACT(T, ZZ, SUP)                                                        \
    {                                                                          \
        const float d0 = 1.0f + fexp2(ZZ[0]);                                  \
        const float d1 = 1.0f + fexp2(ZZ[1]);                                  \
        const float d2 = 1.0f + fexp2(ZZ[2]);                                  \
        const float d3 = 1.0f + fexp2(ZZ[3]);                                  \
        const float m1 = d0 * d1, m2 = d2 * d3;                                \
        const float pq_ = frcp(m1 * m2);                                       \
        const float pif = m2 * pq_, pgo = m1 * pq_;                            \
        const float si = d1 * pif, sf = d0 * pif;                              \
        const float tg = fmaf(-2.0f, d3 * pgo, 1.0f);                          \
        sO[T] = d2 * pgo;                                                      \
        float cn = fmaf(sf, cst[T], si * tg);                                  \
        if (SUP) cn = l1p[T] ? 0.0f : cn;  /* prologue: L1 pairs stay 0 */     \
        cst[T] = cn;                                                           \
        eC[T] = 1.0f + fexp2(LOG2E2 * cn);                                     \
    }

    // one pipelined step, all-register: consume bh/bl, update bh/bl in place.
    // XIN = x[t+2] (float2) to insert for the next step's v.
#define STEP(XIN, SUP)                                                         \
    {                                                                          \
        f32x4 z0 = __builtin_amdgcn_mfma_f32_16x16x32_f16(ahi[0], bh, cb[0], 0, 0, 0); \
        f32x4 z1 = __builtin_amdgcn_mfma_f32_16x16x32_f16(ahi[1], bh, cb[1], 0, 0, 0); \
        f32x4 z2 = __builtin_amdgcn_mfma_f32_16x16x32_f16(ahi[2], bh, cb[2], 0, 0, 0); \
        f32x4 z3 = __builtin_amdgcn_mfma_f32_16x16x32_f16(ahi[3], bh, cb[3], 0, 0, 0); \
        f32x4 z4 = __builtin_amdgcn_mfma_f32_16x16x32_f16(ahi[4], bh, cb[4], 0, 0, 0); \
        z0 = __builtin_amdgcn_mfma_f32_16x16x32_f16(alo[0], bh, z0, 0, 0, 0);  \
        z1 = __builtin_amdgcn_mfma_f32_16x16x32_f16(alo[1], bh, z1, 0, 0, 0);  \
        z2 = __builtin_amdgcn_mfma_f32_16x16x32_f16(alo[2], bh, z2, 0, 0, 0);  \
        z3 = __builtin_amdgcn_mfma_f32_16x16x32_f16(alo[3], bh, z3, 0, 0, 0);  \
        z4 = __builtin_amdgcn_mfma_f32_16x16x32_f16(alo[4], bh, z4, 0, 0, 0);  \
        z0 = __builtin_amdgcn_mfma_f32_16x16x32_f16(ahi[0], bl, z0, 0, 0, 0);  \
        z1 = __builtin_amdgcn_mfma_f32_16x16x32_f16(ahi[1], bl, z1, 0, 0, 0);  \
        z2 = __builtin_amdgcn_mfma_f32_16x16x32_f16(ahi[2], bl, z2, 0, 0, 0);  \
        z3 = __builtin_amdgcn_mfma_f32_16x16x32_f16(ahi[3], bl, z3, 0, 0, 0);  \
        z4 = __builtin_amdgcn_mfma_f32_16x16x32_f16(ahi[4], bl, z4, 0, 0, 0);  \
        float eC[5], sO[5];                                                    \
        ACT(0, z0, SUP) ACT(1, z1, SUP) ACT(2, z2, SUP)                        \
        ACT(3, z3, SUP) ACT(4, z4, SUP)                                        \
        const float p01 = frcp(eC[0] * eC[1]);                                 \
        const float p23 = frcp(eC[2] * eC[3]);                                 \
        const float p4  = frcp(eC[4]);                                         \
        hT[0] = sO[0] * fmaf(-2.0f, eC[1] * p01, 1.0f);                        \
        hT[1] = sO[1] * fmaf(-2.0f, eC[0] * p01, 1.0f);                        \
        hT[2] = sO[2] * fmaf(-2.0f, eC[3] * p23, 1.0f);                        \
        hT[3] = sO[3] * fmaf(-2.0f, eC[2] * p23, 1.0f);                        \
        hT[4] = sO[4] * fmaf(-2.0f, p4, 1.0f);                                 \
        _Pragma("unroll")                                                      \
        for (int T = 0; T < 5; ++T) {                                          \
            const _Float16 hh = (_Float16)hT[T];                               \
            bh[2 + T] = hh;                                                    \
            bl[2 + T] = (_Float16)(hT[T] - (float)hh);                         \
        }                                                                      \
        const _Float16 xa = (_Float16)(XIN).x, xb2 = (_Float16)(XIN).y;        \
        bh[0] = qz ? xa : (_Float16)0.f;                                       \
        bh[1] = qz ? xb2 : (_Float16)0.f;                                      \
        bl[0] = qz ? (_Float16)((XIN).x - (float)xa) : (_Float16)0.f;          \
        bl[1] = qz ? (_Float16)((XIN).y - (float)xb2) : (_Float16)0.f;         \
    }

    // prologue (t=-1): v=[x0,0,0] -> h1[0]; L1 pairs suppressed; insert x[1]
    STEP(x1, 1)

    // main: 32 iters x 16 steps = 512 (t = 0..511); step t inserts x[t+2]
    for (int cc = 0; cc < 32; ++cc) {
        #pragma unroll
        for (int s = 0; s < 8; ++s) STEP(xr0[s], 0)        // t=16cc+s
        #pragma unroll
        for (int i = 0; i < 8; ++i) {                      // reload chunk 2cc+2
            int ti = 16 * cc + 18 + i; if (ti > 511) ti = 511;
            xr0[i] = *(const float2*)(xe + (size_t)ti * BATCH * 2);
        }
        #pragma unroll
        for (int s = 0; s < 8; ++s) STEP(xr1[s], 0)        // t=16cc+8+s
        #pragma unroll
        for (int i = 0; i < 8; ++i) {                      // reload chunk 2cc+3
            int ti = 16 * cc + 26 + i; if (ti > 511) ti = 511;
            xr1[i] = *(const float2*)(xe + (size_t)ti * BATCH * 2);
        }
    }
#undef STEP
#undef ACT

    // ---- FC: L1 pairs of step 511 hold h2[511] ----
    if (q >= 2) hfc[e][q - 2] = hT[2];            // pairs 10,11 -> units 0,1
    hfc[e][2 + q] = hT[3];                        // pairs 12..15 -> units 2..5
    hfc[e][6 + q] = hT[4];                        // pairs 16..19 -> units 6..9
    __syncthreads();
    if (lane < 32) {
        const int ee = lane >> 1, jj = lane & 1;
        float acc = fc_b[jj];
        #pragma unroll
        for (int u = 0; u < 10; ++u)
            acc = fmaf(fc_w[jj * 10 + u], hfc[ee][u], acc);
        out[((size_t)Eb + ee) * 2 + jj] = acc;
    }
}

extern "C" void kernel_launch(void* const* d_in, const int* in_sizes, int n_in,
                              void* d_out, int out_size, void* d_ws, size_t ws_size,
                              hipStream_t stream) {
    const float* x     = (const float*)d_in[0];
    const float* w_ih0 = (const float*)d_in[1];
    const float* w_hh0 = (const float*)d_in[2];
    const float* b_ih0 = (const float*)d_in[3];
    const float* b_hh0 = (const float*)d_in[4];
    const float* w_ih1 = (const float*)d_in[5];
    const float* w_hh1 = (const float*)d_in[6];
    const float* b_ih1 = (const float*)d_in[7];
    const float* b_hh1 = (const float*)d_in[8];
    const float* fc_w  = (const float*)d_in[9];
    const float* fc_b  = (const float*)d_in[10];
    float* out = (float*)d_out;

    const int threads = 64;                   // 1 wave = 16 batch elements
    const int blocks  = BATCH / 16;           // 512 waves
    lstm2_fc_mfma<<<blocks, threads, 0, stream>>>(
        x, w_ih0, w_hh0, b_ih0, b_hh0,
        w_ih1, w_hh1, b_ih1, b_hh1, fc_w, fc_b, out);
}